// Round 2
// 755.737 us; speedup vs baseline: 1.6047x; 1.6047x over previous
//
#include <hip/hip_runtime.h>
#include <math.h>

// Problem constants
#define BB 16
#define LL 128
#define HH 1024
#define VV 50257
#define VP 50260      // padded logits row stride (multiple of 4 -> 16B-aligned rows)
#define NBLOG 786     // ceil(VV/64)

// ---------------------------------------------------------------------------
// Kernel 1: x0 = relu(emb[input[:,0]]),  h0 = einsum(hidden, bridge_w) + bb
// ---------------------------------------------------------------------------
__global__ __launch_bounds__(256) void k_embed_bridge(
    const int* __restrict__ input, const float* __restrict__ hidden,
    const float* __restrict__ emb, const float* __restrict__ bw,
    const float* __restrict__ bb, float* __restrict__ x0, float* __restrict__ h0) {
    int tid = blockIdx.x * 256 + threadIdx.x;     // 0..16383
    int b = tid >> 10;
    int h = tid & (HH - 1);
    int tok = input[b * LL];
    float xv = emb[(long)tok * HH + h];
    x0[tid] = xv > 0.f ? xv : 0.f;
    float acc = bb[0];
    const float* hp = hidden + (long)b * LL * HH + h;
    #pragma unroll 8
    for (int l = 0; l < LL; ++l) acc += hp[(long)l * HH] * bw[l];
    h0[tid] = acc;
}

// ---------------------------------------------------------------------------
// Shared-memory block for the tiled mat-vec16 core.
//  Wl: 64-row x 64-col chunk, row stride 68 dwords (16 float4 + 4 pad) - reads
//      by 16 distinct k-slot addresses land on distinct-ish banks.
//  hc: vector chunk in [k-slot][b] float4 layout, row pad 17 -> uniform banks.
// ---------------------------------------------------------------------------
struct Smem {
    float  Wl[2][64 * 68];     // 34.8 KB double-buffered W chunk
    float4 hc[2][16 * 17];     // 8.7 KB  double-buffered vec chunk
    float  pb[64];             // bias (or -1e30 sentinel) for the 64 rows
    float  redm[4][16];        // per-wave LSE partials
    float  reds[4][16];
};

// ---------------------------------------------------------------------------
// Core: C[row, b] = sum_k W[v0+row, k] * vec[b, k] for a 64-row tile, K=1024.
// 256 thr = 4 waves; wave w owns rows w*16..w*16+15. Lane: ks = lane&15 owns
// k-quads ks of every 64-wide chunk, q4 = lane>>4 owns b-group q4*4..q4*4+3.
// acc[16][4] holds k-slot partials; shfl_xor butterfly over ks finishes dots.
// Double-buffered: global->reg prefetch of chunk c+1 in flight during compute
// of chunk c; ONE barrier per chunk (write buf, barrier, read buf).
// ---------------------------------------------------------------------------
__device__ __forceinline__ void mv64_core(
    const float* __restrict__ W, int v0, int rowclamp,
    const float* __restrict__ vec, Smem& sm, float (&acc)[16][4]) {
    const int t    = threadIdx.x;
    const int lane = t & 63;
    const int w    = t >> 6;
    const int ks   = lane & 15;
    const int q4   = lane >> 4;
    const int srow = t >> 2, sq = t & 3;     // staging: row, base quad
    const int hb   = t >> 4, hq = t & 15;    // vec staging: b, quad

    long grow = v0 + srow; if (grow > rowclamp) grow = rowclamp;
    const float* gW = W + grow * HH + sq * 4;
    const float* gH = vec + hb * HH + hq * 4;

    float4 w0, w1, w2, w3, hstg;
    {   // prologue: chunk 0 into regs
        const float4* p = (const float4*)gW;
        w0 = p[0]; w1 = p[4]; w2 = p[8]; w3 = p[12];
        hstg = *(const float4*)gH;
    }
    #pragma unroll
    for (int r = 0; r < 16; ++r)
        acc[r][0] = acc[r][1] = acc[r][2] = acc[r][3] = 0.f;

    for (int c = 0; c < 16; ++c) {
        const int cur = c & 1;
        float*  WL = sm.Wl[cur];
        float4* HC = sm.hc[cur];
        float4* wr4 = (float4*)(WL + srow * 68);
        wr4[sq]      = w0;
        wr4[sq + 4]  = w1;
        wr4[sq + 8]  = w2;
        wr4[sq + 12] = w3;
        HC[hq * 17 + hb] = hstg;
        if (c < 15) {   // prefetch chunk c+1 (in flight across the compute below)
            const float4* p = (const float4*)(gW + (c + 1) * 64);
            w0 = p[0]; w1 = p[4]; w2 = p[8]; w3 = p[12];
            hstg = *(const float4*)(gH + (c + 1) * 64);
        }
        __syncthreads();   // single barrier/chunk: next iter writes buf[cur^1],
                           // whose readers all passed THIS barrier already.
        float4 h0v = HC[ks * 17 + q4 * 4 + 0];
        float4 h1v = HC[ks * 17 + q4 * 4 + 1];
        float4 h2v = HC[ks * 17 + q4 * 4 + 2];
        float4 h3v = HC[ks * 17 + q4 * 4 + 3];
        const float* wr = WL + (w * 16) * 68 + ks * 4;
        #pragma unroll
        for (int r = 0; r < 16; ++r) {
            float4 wv = *(const float4*)(wr + r * 68);
            acc[r][0] += wv.x * h0v.x + wv.y * h0v.y + wv.z * h0v.z + wv.w * h0v.w;
            acc[r][1] += wv.x * h1v.x + wv.y * h1v.y + wv.z * h1v.z + wv.w * h1v.w;
            acc[r][2] += wv.x * h2v.x + wv.y * h2v.y + wv.z * h2v.z + wv.w * h2v.w;
            acc[r][3] += wv.x * h3v.x + wv.y * h3v.y + wv.z * h3v.z + wv.w * h3v.w;
        }
    }
    // finish dot products: butterfly-sum over the 16 k-slot lanes
    #pragma unroll
    for (int m = 1; m <= 8; m <<= 1) {
        #pragma unroll
        for (int r = 0; r < 16; ++r) {
            acc[r][0] += __shfl_xor(acc[r][0], m, 64);
            acc[r][1] += __shfl_xor(acc[r][1], m, 64);
            acc[r][2] += __shfl_xor(acc[r][2], m, 64);
            acc[r][3] += __shfl_xor(acc[r][3], m, 64);
        }
    }
}

// ---------------------------------------------------------------------------
// Kernel 2: both GRU gate GEMVs. Blocks 0..47: w_ih·x0 -> gi_t; 48..95:
// w_hh·h0 -> gh_t. Output layout gi_t[g*16+b] (what k_combine expects).
// ---------------------------------------------------------------------------
__global__ __launch_bounds__(256) void k_gates(
    const float* __restrict__ x0, const float* __restrict__ h0,
    const float* __restrict__ w_ih, const float* __restrict__ w_hh,
    const float* __restrict__ b_ih, const float* __restrict__ b_hh,
    float* __restrict__ gi_t, float* __restrict__ gh_t) {
    __shared__ Smem sm;
    const int blk = blockIdx.x;
    const bool second = blk >= 48;
    const float* W    = second ? w_hh : w_ih;
    const float* vec  = second ? h0 : x0;
    const float* bias = second ? b_hh : b_ih;
    float* outp       = second ? gh_t : gi_t;
    const int g0 = (second ? blk - 48 : blk) * 64;
    const int t = threadIdx.x;
    if (t < 64) sm.pb[t] = bias[g0 + t];

    float acc[16][4];
    mv64_core(W, g0, 3 * HH - 1, vec, sm, acc);

    const int lane = t & 63, w = t >> 6, ks = lane & 15, q4 = lane >> 4;
    #pragma unroll
    for (int r = 0; r < 16; ++r) {
        if (ks == r) {
            float bs = sm.pb[w * 16 + r];
            float4 o = make_float4(acc[r][0] + bs, acc[r][1] + bs,
                                   acc[r][2] + bs, acc[r][3] + bs);
            *(float4*)(outp + (g0 + w * 16 + r) * 16 + q4 * 4) = o;
        }
    }
}

// ---------------------------------------------------------------------------
// Kernel 2b: GRU gate combine -> h1 [b-major]. 16384 threads. (unchanged)
// ---------------------------------------------------------------------------
__global__ __launch_bounds__(256) void k_combine(
    const float* __restrict__ gi_t, const float* __restrict__ gh_t,
    const float* __restrict__ h0, float* __restrict__ h1) {
    int tid = blockIdx.x * 256 + threadIdx.x;
    int h = tid >> 4;
    int b = tid & 15;
    float ir = gi_t[h * 16 + b],             hr = gh_t[h * 16 + b];
    float iz = gi_t[(HH + h) * 16 + b],      hz = gh_t[(HH + h) * 16 + b];
    float in_ = gi_t[(2 * HH + h) * 16 + b], hn = gh_t[(2 * HH + h) * 16 + b];
    float r = 1.f / (1.f + expf(-(ir + hr)));
    float z = 1.f / (1.f + expf(-(iz + hz)));
    float n = tanhf(in_ + r * hn);
    float h0v = h0[b * HH + h];
    h1[b * HH + h] = (1.f - z) * n + z * h0v;
}

// ---------------------------------------------------------------------------
// Kernel 3: logits tile + fused per-block LSE partials (max & sumexp per b).
// Stores logits b-major with padded stride VP; writes pmax/psum[block][b].
// ---------------------------------------------------------------------------
__global__ __launch_bounds__(256) void k_logits_lse(
    const float* __restrict__ h1, const float* __restrict__ proj_w,
    const float* __restrict__ proj_b, float* __restrict__ logits,
    float* __restrict__ pmax, float* __restrict__ psum) {
    __shared__ Smem sm;
    const int t = threadIdx.x;
    const int v0 = blockIdx.x * 64;
    if (t < 64) {
        int gv = v0 + t;
        sm.pb[t] = (gv < VV) ? proj_b[gv] : -1e30f;   // sentinel kills padded rows
    }
    float acc[16][4];
    mv64_core(proj_w, v0, VV - 1, h1, sm, acc);

    const int lane = t & 63, w = t >> 6, ks = lane & 15, q4 = lane >> 4;
    // bias + per-b running max over this wave's 16 rows (redundant per ks-lane)
    float mx[4] = {-1e30f, -1e30f, -1e30f, -1e30f};
    #pragma unroll
    for (int r = 0; r < 16; ++r) {
        float pb = sm.pb[w * 16 + r];
        acc[r][0] += pb; acc[r][1] += pb; acc[r][2] += pb; acc[r][3] += pb;
        mx[0] = fmaxf(mx[0], acc[r][0]); mx[1] = fmaxf(mx[1], acc[r][1]);
        mx[2] = fmaxf(mx[2], acc[r][2]); mx[3] = fmaxf(mx[3], acc[r][3]);
    }
    float sv[4] = {0.f, 0.f, 0.f, 0.f};
    #pragma unroll
    for (int r = 0; r < 16; ++r) {
        sv[0] += __expf(acc[r][0] - mx[0]); sv[1] += __expf(acc[r][1] - mx[1]);
        sv[2] += __expf(acc[r][2] - mx[2]); sv[3] += __expf(acc[r][3] - mx[3]);
    }
    // store logits: lane ks==r owns row r of its wave, 4 b's each
    #pragma unroll
    for (int r = 0; r < 16; ++r) {
        if (ks == r) {
            int v = v0 + w * 16 + r;
            if (v < VV) {
                logits[(long)(q4 * 4 + 0) * VP + v] = acc[r][0];
                logits[(long)(q4 * 4 + 1) * VP + v] = acc[r][1];
                logits[(long)(q4 * 4 + 2) * VP + v] = acc[r][2];
                logits[(long)(q4 * 4 + 3) * VP + v] = acc[r][3];
            }
        }
    }
    if (ks == 0) {
        #pragma unroll
        for (int i = 0; i < 4; ++i) {
            sm.redm[w][q4 * 4 + i] = mx[i];
            sm.reds[w][q4 * 4 + i] = sv[i];
        }
    }
    __syncthreads();
    if (t < 16) {   // combine 4 waves -> per-block partial
        float M = sm.redm[0][t];
        M = fmaxf(M, sm.redm[1][t]); M = fmaxf(M, sm.redm[2][t]); M = fmaxf(M, sm.redm[3][t]);
        float S = sm.reds[0][t] * __expf(sm.redm[0][t] - M)
                + sm.reds[1][t] * __expf(sm.redm[1][t] - M)
                + sm.reds[2][t] * __expf(sm.redm[2][t] - M)
                + sm.reds[3][t] * __expf(sm.redm[3][t] - M);
        pmax[blockIdx.x * 16 + t] = M;
        psum[blockIdx.x * 16 + t] = S;
    }
}

// ---------------------------------------------------------------------------
// Kernel 4: reduce per-block LSE partials -> C[b]. 16 blocks x 1 wave.
// ---------------------------------------------------------------------------
__global__ __launch_bounds__(64) void k_lse_red(
    const float* __restrict__ pmax, const float* __restrict__ psum,
    float* __restrict__ C) {
    const int b = blockIdx.x;
    const int t = threadIdx.x;
    float M = -1e30f;
    for (int i = t; i < NBLOG; i += 64) M = fmaxf(M, pmax[i * 16 + b]);
    #pragma unroll
    for (int m = 32; m >= 1; m >>= 1) M = fmaxf(M, __shfl_xor(M, m, 64));
    float S = 0.f;
    for (int i = t; i < NBLOG; i += 64)
        S += psum[i * 16 + b] * __expf(pmax[i * 16 + b] - M);
    #pragma unroll
    for (int m = 32; m >= 1; m >>= 1) S += __shfl_xor(S, m, 64);
    if (t == 0) C[b] = M + logf(S);
}

// ---------------------------------------------------------------------------
// Kernel 5: broadcast. Each block owns (b, 1024-wide v chunk): reads the chunk
// ONCE into registers, writes it to all 127 t-rows. Pure write stream.
// (dword stores on purpose: VV is odd, so odd rows are not float4-aligned)
// ---------------------------------------------------------------------------
__global__ __launch_bounds__(256) void k_bcast(
    const float* __restrict__ logits, const float* __restrict__ C,
    float* __restrict__ out) {
    const int b = blockIdx.y;
    const int t = threadIdx.x;
    const int v0 = blockIdx.x * 1024 + t;
    const float cb = C[b];
    const float* src = logits + (long)b * VP;
    const bool g0 = v0 < VV, g1 = v0 + 256 < VV, g2 = v0 + 512 < VV, g3 = v0 + 768 < VV;
    const float f0 = g0 ? src[v0]       - cb : 0.f;
    const float f1 = g1 ? src[v0 + 256] - cb : 0.f;
    const float f2 = g2 ? src[v0 + 512] - cb : 0.f;
    const float f3 = g3 ? src[v0 + 768] - cb : 0.f;
    long base = (long)b * 127 * VV + v0;
    for (int r = 0; r < 127; ++r) {
        float* d = out + base;
        if (g0) d[0]   = f0;
        if (g1) d[256] = f1;
        if (g2) d[512] = f2;
        if (g3) d[768] = f3;
        base += VV;
    }
}

extern "C" void kernel_launch(void* const* d_in, const int* in_sizes, int n_in,
                              void* d_out, int out_size, void* d_ws, size_t ws_size,
                              hipStream_t stream) {
    const int*   input    = (const int*)  d_in[0];
    const float* hidden   = (const float*)d_in[1];
    const float* emb      = (const float*)d_in[2];
    const float* bridge_w = (const float*)d_in[3];
    const float* bridge_b = (const float*)d_in[4];
    const float* w_ih     = (const float*)d_in[5];
    const float* w_hh     = (const float*)d_in[6];
    const float* b_ih     = (const float*)d_in[7];
    const float* b_hh     = (const float*)d_in[8];
    const float* proj_w   = (const float*)d_in[9];
    const float* proj_b   = (const float*)d_in[10];
    float* out = (float*)d_out;

    // Workspace (floats). logits aliases gi_t/gh_t (dead after k_combine).
    float* ws    = (float*)d_ws;
    float* x0    = ws;               // 16384
    float* h0v   = ws + 16384;       // 16384
    float* h1v   = ws + 32768;       // 16384
    float* Cb    = ws + 49152;       // 16
    float* pmaxb = ws + 49168;       // 12576
    float* psumb = ws + 61744;       // 12576
    float* gi_t  = ws + 74320;       // 49152
    float* gh_t  = ws + 123472;      // 49152
    float* logits = ws + 74320;      // 16*VP = 804160 (alias; ends at 878480)

    k_embed_bridge<<<dim3(64), dim3(256), 0, stream>>>(input, hidden, emb,
                                                       bridge_w, bridge_b, x0, h0v);
    k_gates<<<dim3(96), dim3(256), 0, stream>>>(x0, h0v, w_ih, w_hh, b_ih, b_hh,
                                                gi_t, gh_t);
    k_combine<<<dim3(64), dim3(256), 0, stream>>>(gi_t, gh_t, h0v, h1v);
    k_logits_lse<<<dim3(NBLOG), dim3(256), 0, stream>>>(h1v, proj_w, proj_b,
                                                        logits, pmaxb, psumb);
    k_lse_red<<<dim3(16), dim3(64), 0, stream>>>(pmaxb, psumb, Cb);
    k_bcast<<<dim3(50, 16), dim3(256), 0, stream>>>(logits, Cb, out);
}